// Round 5
// baseline (1142.359 us; speedup 1.0000x reference)
//
#include <hip/hip_runtime.h>

#define NFEAT 256
#define GS 32
#define NG 8
#define BATCH 32
#define HW 4096
#define NTOT (BATCH*HW)   // 131072 samples per channel
#define EPSV 1e-5f

// ws layout (float offsets)
#define RPART_SZ (NG*64*1024)                 // 524288 floats
#define SPART_OFF (RPART_SZ)                  // 8*64*32 = 16384
#define WMT_OFF   (SPART_OFF + NG*64*32)      // 8*1024
#define BETA_OFF  (WMT_OFF + NG*1024)         // 8*32

// ---------------------------------------------------------------------------
// Kernel 1: per-(g,b,half) partial raw gram R = X X^T and channel sums S.
// History: R2/R3 (direct strided loads) = TA-throughput-bound at 169us: each
// wave-load carried only 128B unique over 8 broadcast addresses (64 lane-slots
// burned), invariant to occupancy. R5 (global_load_lds staging) = 1.9 GB of
// phantom HBM traffic (FETCH 697MB=5.2x, WRITE 1.2GB vs 2.4MB legit), 478us.
// R6: SAME verified compute structure as R5, staging via registers instead:
//  - after the chunk barrier, each wave issues 2 dense global_load_dwordx4
//    (lane l -> samples l*4.. of its row: 1024B contiguous per instruction,
//    all 64 lane-slots useful -> fixes the R2 TA bottleneck, 4096->256 VMEM
//    instrs per block);
//  - vmcnt drain sits AFTER the 16-step FMA phase, right before the
//    ds_write_b128 into the back buffer (T14 async-split): HBM latency hides
//    under compute;
//  - ds_write into buf[bb] pre-barrier is safe: buf[bb] was last read in
//    chunk ck-1, finished before the barrier that opened chunk ck.
// Compute (verified in R5): 16 waves = 4 sample-slices x 4 tiles of 16x16;
// lane = 8x8 grid, 2x2 acc (4 VGPRs). ds_read_b128 8-way broadcast, 2-way
// bank alias only (free); pad 260 = 4 mod 32.
// ---------------------------------------------------------------------------
__global__ __launch_bounds__(1024) void dbn_stats(const float* __restrict__ x,
                                                  float* __restrict__ Rpart,
                                                  float* __restrict__ Spart) {
    __shared__ float buf[2][32][260];   // 66.6 KB -> 2 blocks/CU
    __shared__ float sscr[4][32];       // channel-sum partials per sp

    int bx = blockIdx.x;            // 0..511
    int g  = bx >> 6;
    int pb = bx & 63;               // b*2 + h
    int b  = pb >> 1, h = pb & 1;
    int tid = threadIdx.x;
    int w  = tid >> 6;              // wave 0..15
    int l  = tid & 63;
    int sp = w >> 2;                // sample slice 0..3 (64 samples of chunk)
    int t  = w & 3;                 // tile id: (tr1, tc1) in 2x2 grid of 16x16
    int tr1 = t >> 1, tc1 = t & 1;
    int li = l >> 3, lj = l & 7;    // lane 8x8 grid; lane owns 2x2 entries

    const float* xg = x + ((size_t)(b*NFEAT + g*GS))*HW + h*2048;

    int r0 = w*2, r1 = w*2 + 1;     // rows this wave stages each chunk
    int rrow = tr1*16 + 2*li;       // gram rows rrow, rrow+1
    int crow = tc1*16 + 2*lj;       // gram cols crow, crow+1

    float acc00 = 0.f, acc01 = 0.f, acc10 = 0.f, acc11 = 0.f;
    float srow0 = 0.f, srow1 = 0.f;

    // stage chunk 0 into buf[0] (through regs; vmcnt drains at the ds_write)
    {
        float4 st0 = *(const float4*)(xg + (size_t)r0*HW + l*4);
        float4 st1 = *(const float4*)(xg + (size_t)r1*HW + l*4);
        *(float4*)&buf[0][r0][l*4] = st0;
        *(float4*)&buf[0][r1][l*4] = st1;
    }

    #pragma unroll 1
    for (int ck = 0; ck < 8; ++ck) {
        __syncthreads();   // staged data visible + prev compute done
        int cur = ck & 1, bb = cur ^ 1;
        float4 st0, st1;
        bool pf = (ck < 7);
        if (pf) {          // issue next chunk's loads NOW; drain after compute
            st0 = *(const float4*)(xg + (size_t)r0*HW + (ck+1)*256 + l*4);
            st1 = *(const float4*)(xg + (size_t)r1*HW + (ck+1)*256 + l*4);
        }
        int soff = sp*64;
        #pragma unroll
        for (int s = 0; s < 16; ++s) {
            int sa = soff + s*4;
            float4 ra0 = *(const float4*)&buf[cur][rrow    ][sa];
            float4 ra1 = *(const float4*)&buf[cur][rrow + 1][sa];
            float4 cb0 = *(const float4*)&buf[cur][crow    ][sa];
            float4 cb1 = *(const float4*)&buf[cur][crow + 1][sa];
            acc00 = fmaf(ra0.x, cb0.x, acc00); acc00 = fmaf(ra0.y, cb0.y, acc00);
            acc00 = fmaf(ra0.z, cb0.z, acc00); acc00 = fmaf(ra0.w, cb0.w, acc00);
            acc01 = fmaf(ra0.x, cb1.x, acc01); acc01 = fmaf(ra0.y, cb1.y, acc01);
            acc01 = fmaf(ra0.z, cb1.z, acc01); acc01 = fmaf(ra0.w, cb1.w, acc01);
            acc10 = fmaf(ra1.x, cb0.x, acc10); acc10 = fmaf(ra1.y, cb0.y, acc10);
            acc10 = fmaf(ra1.z, cb0.z, acc10); acc10 = fmaf(ra1.w, cb0.w, acc10);
            acc11 = fmaf(ra1.x, cb1.x, acc11); acc11 = fmaf(ra1.y, cb1.y, acc11);
            acc11 = fmaf(ra1.z, cb1.z, acc11); acc11 = fmaf(ra1.w, cb1.w, acc11);
            if (tc1 == 0) {   // wave-uniform branch; tc1==0 waves own row sums
                srow0 += (ra0.x + ra0.y) + (ra0.z + ra0.w);
                srow1 += (ra1.x + ra1.y) + (ra1.z + ra1.w);
            }
        }
        if (pf) {          // vmcnt(0) lands here, after ~1000cy of compute
            *(float4*)&buf[bb][r0][l*4] = st0;
            *(float4*)&buf[bb][r1][l*4] = st1;
        }
    }

    __syncthreads();   // all compute done; safe to overlay scratch on buf

    // sp-reduction scratch: [sp*4+t][lane][4 entries] = 16 KB inside buf
    float* scr = &buf[0][0][0];
    scr[((sp*4 + t)*64 + l)*4 + 0] = acc00;
    scr[((sp*4 + t)*64 + l)*4 + 1] = acc01;
    scr[((sp*4 + t)*64 + l)*4 + 2] = acc10;
    scr[((sp*4 + t)*64 + l)*4 + 3] = acc11;
    if (tc1 == 0 && lj == 0) {
        sscr[sp][tr1*16 + 2*li + 0] = srow0;
        sscr[sp][tr1*16 + 2*li + 1] = srow1;
    }
    __syncthreads();

    // 1024 threads <-> 1024 gram entries: sum the 4 sp-slices, store.
    {
        int tt = tid >> 8;            // tile 0..3
        int ll = (tid >> 2) & 63;     // lane slot
        int e  = tid & 3;             // entry 0..3 (rr*2+cc)
        float s = scr[((0*4 + tt)*64 + ll)*4 + e]
                + scr[((1*4 + tt)*64 + ll)*4 + e]
                + scr[((2*4 + tt)*64 + ll)*4 + e]
                + scr[((3*4 + tt)*64 + ll)*4 + e];
        int ttr = tt >> 1, ttc = tt & 1;
        int lli = ll >> 3, llj = ll & 7;
        int row = ttr*16 + 2*lli + (e >> 1);
        int col = ttc*16 + 2*llj + (e & 1);
        Rpart[(size_t)(g*64 + pb)*1024 + row*32 + col] = s;
    }
    if (tid < 32) {
        float s = sscr[0][tid] + sscr[1][tid] + sscr[2][tid] + sscr[3][tid];
        Spart[(size_t)(g*64 + pb)*32 + tid] = s;
    }
}

// ---------------------------------------------------------------------------
// Kernel 2: per-group solver — EXACT round-1 version (non-stats = 226us
// measured there; unchanged pending counters).
// ---------------------------------------------------------------------------
__global__ __launch_bounds__(1024) void dbn_solver(const float* __restrict__ Rpart, const float* __restrict__ Spart,
                           const float* __restrict__ weight, const float* __restrict__ bias,
                           float* __restrict__ wmT, float* __restrict__ beta) {
    __shared__ float Y[1024], Z[1024], T[1024], S[32], M[32];
    __shared__ float sh_s;
    int g = blockIdx.x;
    int tid = threadIdx.x;
    int c = tid >> 5, d = tid & 31;

    if (tid < 32) {
        float s = 0.f;
        #pragma unroll 4
        for (int pb = 0; pb < 64; ++pb) s += Spart[(size_t)(g*64 + pb)*32 + tid];
        S[tid] = s;
        M[tid] = s / (float)NTOT;
    }
    float rs = 0.f;
    #pragma unroll 4
    for (int pb = 0; pb < 64; ++pb) rs += Rpart[(size_t)(g*64 + pb)*1024 + tid];
    __syncthreads();

    const float invN = 1.0f/(float)NTOT;
    float v = rs - S[c]*S[d]*invN;
    if (c == d) v += EPSV;
    T[tid] = v;
    __syncthreads();

    if (tid == 0) {
        float tr = 0.f;
        for (int k = 0; k < 32; ++k) tr += T[k*33];
        sh_s = tr / 32.0f;
    }
    __syncthreads();
    float sc = sh_s;
    float invs = 1.0f / sc;

    Y[tid] = v * invs;
    Z[tid] = (c == d) ? 1.0f : 0.0f;
    __syncthreads();

    for (int it = 0; it < 8; ++it) {
        float s2 = 0.f;
        #pragma unroll
        for (int k = 0; k < 32; ++k) s2 = fmaf(Z[c*32 + k], Y[k*32 + d], s2);
        float a = ((c == d) ? 3.0f : 0.0f) - s2;
        __syncthreads();
        T[tid] = a;
        __syncthreads();
        float sy = 0.f, sz = 0.f;
        #pragma unroll
        for (int k = 0; k < 32; ++k) {
            sy = fmaf(Y[c*32 + k], T[k*32 + d], sy);
            sz = fmaf(T[c*32 + k], Z[k*32 + d], sz);
        }
        __syncthreads();
        Y[tid] = 0.5f*sy;
        Z[tid] = 0.5f*sz;
        __syncthreads();
    }

    float wfac = rsqrtf(sc);   // sigma^{-1/2} = Z / sqrt(s)
    wmT[(size_t)g*1024 + d*32 + c] = Z[tid]*wfac*weight[g*GS + c];  // transposed + weight-folded
    if (tid < 32) {
        float s2 = 0.f;
        #pragma unroll
        for (int k = 0; k < 32; ++k) s2 = fmaf(Z[tid*32 + k], M[k], s2);
        beta[g*GS + tid] = -s2*wfac*weight[g*GS + tid] + bias[g*GS + tid];
    }
}

// ---------------------------------------------------------------------------
// Kernel 3: whiten — EXACT round-1 version (unchanged pending counters).
// ---------------------------------------------------------------------------
__global__ __launch_bounds__(256) void dbn_whiten(const float* __restrict__ x,
                                                  const float* __restrict__ wmT,
                                                  const float* __restrict__ beta,
                                                  float* __restrict__ out) {
    int bx = blockIdx.x;            // 0..4095
    int gb = bx >> 4;               // 0..255
    int chunk = bx & 15;
    int b = gb >> 3, g = gb & 7;
    size_t base = ((size_t)(b*NFEAT + g*GS))*HW + chunk*256 + threadIdx.x;
    const float* wg = wmT + (size_t)g*1024;
    const float* bg = beta + (size_t)g*GS;

    float v[32];
    #pragma unroll
    for (int d = 0; d < 32; ++d) v[d] = x[base + (size_t)d*HW];

    float acc[32];
    #pragma unroll
    for (int c = 0; c < 32; ++c) acc[c] = bg[c];

    #pragma unroll
    for (int d = 0; d < 32; ++d) {
        float vd = v[d];
        #pragma unroll
        for (int c = 0; c < 32; ++c) acc[c] = fmaf(wg[d*32 + c], vd, acc[c]);
    }

    #pragma unroll
    for (int c = 0; c < 32; ++c) out[base + (size_t)c*HW] = acc[c];
}

extern "C" void kernel_launch(void* const* d_in, const int* in_sizes, int n_in,
                              void* d_out, int out_size, void* d_ws, size_t ws_size,
                              hipStream_t stream) {
    const float* x      = (const float*)d_in[0];
    const float* weight = (const float*)d_in[1];
    const float* bias   = (const float*)d_in[2];
    float* out = (float*)d_out;
    float* ws  = (float*)d_ws;

    float* Rpart = ws;
    float* Spart = ws + SPART_OFF;
    float* wmT   = ws + WMT_OFF;
    float* beta  = ws + BETA_OFF;

    dbn_stats <<<512, 1024, 0, stream>>>(x, Rpart, Spart);
    dbn_solver<<<NG, 1024, 0, stream>>>(Rpart, Spart, weight, bias, wmT, beta);
    dbn_whiten<<<4096, 256, 0, stream>>>(x, wmT, beta, out);
}

// Round 6
// 322.727 us; speedup vs baseline: 3.5397x; 3.5397x over previous
//
#include <hip/hip_runtime.h>

#define NFEAT 256
#define GS 32
#define NG 8
#define BATCH 32
#define HW 4096
#define NTOT (BATCH*HW)   // 131072 samples per channel
#define EPSV 1e-5f

// ws layout (float offsets)
#define RPART_SZ (NG*64*1024)                 // 524288 floats
#define SPART_OFF (RPART_SZ)                  // 8*64*32 = 16384
#define WMT_OFF   (SPART_OFF + NG*64*32)      // 8*1024
#define BETA_OFF  (WMT_OFF + NG*1024)         // 8*32

// ---------------------------------------------------------------------------
// Kernel 1: per-(g,b,half) partial raw gram R = X X^T and channel sums S.
// R6 post-mortem (the unifying diagnosis of ALL four spill events R1/R4/R5/R6):
// with 1024-thread blocks and no min-waves arg, the compiler caps VGPR at the
// 8-waves/SIMD boundary = 64; the fully-unrolled 16-step ds_read loop hoists
// dozens of b128 destinations above the cap -> per-iteration scratch spill
// (R6: 2.59 GB WRITE, 620 B/thread/chunk, VALUBusy 5%, 923us). VGPR_Count=64
// exactly == the cap is the fingerprint.
// R7 (two-line fix, single variable):
//  1. __launch_bounds__(1024, 1): VGPR budget -> 256. 1 block/CU is fine:
//     R3 proved this kernel doesn't live on occupancy; overlap is in-block.
//  2. #pragma unroll 4 on the s-loop: bounds the ds_read hoisting window
//     (~16 VGPRs) so live pressure stays ~60-100.
// Structure otherwise IDENTICAL to R6 (verified correct, 0 bank conflicts):
// reg-staged dense global_load_dwordx4 (1024B/instr, all lane-slots useful),
// vmcnt drain after compute (T14), LDS double-buffer, 4 sp-slices x 4 tiles,
// 2x2 acc/lane.
// ---------------------------------------------------------------------------
__global__ __launch_bounds__(1024, 1) void dbn_stats(const float* __restrict__ x,
                                                     float* __restrict__ Rpart,
                                                     float* __restrict__ Spart) {
    __shared__ float buf[2][32][260];   // 66.6 KB
    __shared__ float sscr[4][32];       // channel-sum partials per sp

    int bx = blockIdx.x;            // 0..511
    int g  = bx >> 6;
    int pb = bx & 63;               // b*2 + h
    int b  = pb >> 1, h = pb & 1;
    int tid = threadIdx.x;
    int w  = tid >> 6;              // wave 0..15
    int l  = tid & 63;
    int sp = w >> 2;                // sample slice 0..3 (64 samples of chunk)
    int t  = w & 3;                 // tile id: (tr1, tc1) in 2x2 grid of 16x16
    int tr1 = t >> 1, tc1 = t & 1;
    int li = l >> 3, lj = l & 7;    // lane 8x8 grid; lane owns 2x2 entries

    const float* xg = x + ((size_t)(b*NFEAT + g*GS))*HW + h*2048;

    int r0 = w*2, r1 = w*2 + 1;     // rows this wave stages each chunk
    int rrow = tr1*16 + 2*li;       // gram rows rrow, rrow+1
    int crow = tc1*16 + 2*lj;       // gram cols crow, crow+1

    float acc00 = 0.f, acc01 = 0.f, acc10 = 0.f, acc11 = 0.f;
    float srow0 = 0.f, srow1 = 0.f;

    // stage chunk 0 into buf[0]
    {
        float4 st0 = *(const float4*)(xg + (size_t)r0*HW + l*4);
        float4 st1 = *(const float4*)(xg + (size_t)r1*HW + l*4);
        *(float4*)&buf[0][r0][l*4] = st0;
        *(float4*)&buf[0][r1][l*4] = st1;
    }

    #pragma unroll 1
    for (int ck = 0; ck < 8; ++ck) {
        __syncthreads();   // staged data visible + prev compute done
        int cur = ck & 1, bb = cur ^ 1;
        float4 st0, st1;
        bool pf = (ck < 7);
        if (pf) {          // issue next chunk's loads NOW; drain after compute
            st0 = *(const float4*)(xg + (size_t)r0*HW + (ck+1)*256 + l*4);
            st1 = *(const float4*)(xg + (size_t)r1*HW + (ck+1)*256 + l*4);
        }
        int soff = sp*64;
        #pragma unroll 4
        for (int s = 0; s < 16; ++s) {
            int sa = soff + s*4;
            float4 ra0 = *(const float4*)&buf[cur][rrow    ][sa];
            float4 ra1 = *(const float4*)&buf[cur][rrow + 1][sa];
            float4 cb0 = *(const float4*)&buf[cur][crow    ][sa];
            float4 cb1 = *(const float4*)&buf[cur][crow + 1][sa];
            acc00 = fmaf(ra0.x, cb0.x, acc00); acc00 = fmaf(ra0.y, cb0.y, acc00);
            acc00 = fmaf(ra0.z, cb0.z, acc00); acc00 = fmaf(ra0.w, cb0.w, acc00);
            acc01 = fmaf(ra0.x, cb1.x, acc01); acc01 = fmaf(ra0.y, cb1.y, acc01);
            acc01 = fmaf(ra0.z, cb1.z, acc01); acc01 = fmaf(ra0.w, cb1.w, acc01);
            acc10 = fmaf(ra1.x, cb0.x, acc10); acc10 = fmaf(ra1.y, cb0.y, acc10);
            acc10 = fmaf(ra1.z, cb0.z, acc10); acc10 = fmaf(ra1.w, cb0.w, acc10);
            acc11 = fmaf(ra1.x, cb1.x, acc11); acc11 = fmaf(ra1.y, cb1.y, acc11);
            acc11 = fmaf(ra1.z, cb1.z, acc11); acc11 = fmaf(ra1.w, cb1.w, acc11);
            if (tc1 == 0) {   // wave-uniform branch; tc1==0 waves own row sums
                srow0 += (ra0.x + ra0.y) + (ra0.z + ra0.w);
                srow1 += (ra1.x + ra1.y) + (ra1.z + ra1.w);
            }
        }
        if (pf) {          // vmcnt(0) lands here, after ~1000cy of compute
            *(float4*)&buf[bb][r0][l*4] = st0;
            *(float4*)&buf[bb][r1][l*4] = st1;
        }
    }

    __syncthreads();   // all compute done; safe to overlay scratch on buf

    // sp-reduction scratch: [sp*4+t][lane][4 entries] = 16 KB inside buf
    float* scr = &buf[0][0][0];
    scr[((sp*4 + t)*64 + l)*4 + 0] = acc00;
    scr[((sp*4 + t)*64 + l)*4 + 1] = acc01;
    scr[((sp*4 + t)*64 + l)*4 + 2] = acc10;
    scr[((sp*4 + t)*64 + l)*4 + 3] = acc11;
    if (tc1 == 0 && lj == 0) {
        sscr[sp][tr1*16 + 2*li + 0] = srow0;
        sscr[sp][tr1*16 + 2*li + 1] = srow1;
    }
    __syncthreads();

    // 1024 threads <-> 1024 gram entries: sum the 4 sp-slices, store.
    {
        int tt = tid >> 8;            // tile 0..3
        int ll = (tid >> 2) & 63;     // lane slot
        int e  = tid & 3;             // entry 0..3 (rr*2+cc)
        float s = scr[((0*4 + tt)*64 + ll)*4 + e]
                + scr[((1*4 + tt)*64 + ll)*4 + e]
                + scr[((2*4 + tt)*64 + ll)*4 + e]
                + scr[((3*4 + tt)*64 + ll)*4 + e];
        int ttr = tt >> 1, ttc = tt & 1;
        int lli = ll >> 3, llj = ll & 7;
        int row = ttr*16 + 2*lli + (e >> 1);
        int col = ttc*16 + 2*llj + (e & 1);
        Rpart[(size_t)(g*64 + pb)*1024 + row*32 + col] = s;
    }
    if (tid < 32) {
        float s = sscr[0][tid] + sscr[1][tid] + sscr[2][tid] + sscr[3][tid];
        Spart[(size_t)(g*64 + pb)*32 + tid] = s;
    }
}

// ---------------------------------------------------------------------------
// Kernel 2: per-group solver — EXACT round-1 version (non-stats = 226us
// measured there; unchanged pending counters).
// ---------------------------------------------------------------------------
__global__ __launch_bounds__(1024) void dbn_solver(const float* __restrict__ Rpart, const float* __restrict__ Spart,
                           const float* __restrict__ weight, const float* __restrict__ bias,
                           float* __restrict__ wmT, float* __restrict__ beta) {
    __shared__ float Y[1024], Z[1024], T[1024], S[32], M[32];
    __shared__ float sh_s;
    int g = blockIdx.x;
    int tid = threadIdx.x;
    int c = tid >> 5, d = tid & 31;

    if (tid < 32) {
        float s = 0.f;
        #pragma unroll 4
        for (int pb = 0; pb < 64; ++pb) s += Spart[(size_t)(g*64 + pb)*32 + tid];
        S[tid] = s;
        M[tid] = s / (float)NTOT;
    }
    float rs = 0.f;
    #pragma unroll 4
    for (int pb = 0; pb < 64; ++pb) rs += Rpart[(size_t)(g*64 + pb)*1024 + tid];
    __syncthreads();

    const float invN = 1.0f/(float)NTOT;
    float v = rs - S[c]*S[d]*invN;
    if (c == d) v += EPSV;
    T[tid] = v;
    __syncthreads();

    if (tid == 0) {
        float tr = 0.f;
        for (int k = 0; k < 32; ++k) tr += T[k*33];
        sh_s = tr / 32.0f;
    }
    __syncthreads();
    float sc = sh_s;
    float invs = 1.0f / sc;

    Y[tid] = v * invs;
    Z[tid] = (c == d) ? 1.0f : 0.0f;
    __syncthreads();

    for (int it = 0; it < 8; ++it) {
        float s2 = 0.f;
        #pragma unroll
        for (int k = 0; k < 32; ++k) s2 = fmaf(Z[c*32 + k], Y[k*32 + d], s2);
        float a = ((c == d) ? 3.0f : 0.0f) - s2;
        __syncthreads();
        T[tid] = a;
        __syncthreads();
        float sy = 0.f, sz = 0.f;
        #pragma unroll
        for (int k = 0; k < 32; ++k) {
            sy = fmaf(Y[c*32 + k], T[k*32 + d], sy);
            sz = fmaf(T[c*32 + k], Z[k*32 + d], sz);
        }
        __syncthreads();
        Y[tid] = 0.5f*sy;
        Z[tid] = 0.5f*sz;
        __syncthreads();
    }

    float wfac = rsqrtf(sc);   // sigma^{-1/2} = Z / sqrt(s)
    wmT[(size_t)g*1024 + d*32 + c] = Z[tid]*wfac*weight[g*GS + c];  // transposed + weight-folded
    if (tid < 32) {
        float s2 = 0.f;
        #pragma unroll
        for (int k = 0; k < 32; ++k) s2 = fmaf(Z[tid*32 + k], M[k], s2);
        beta[g*GS + tid] = -s2*wfac*weight[g*GS + tid] + bias[g*GS + tid];
    }
}

// ---------------------------------------------------------------------------
// Kernel 3: whiten — EXACT round-1 version (unchanged pending counters).
// ---------------------------------------------------------------------------
__global__ __launch_bounds__(256) void dbn_whiten(const float* __restrict__ x,
                                                  const float* __restrict__ wmT,
                                                  const float* __restrict__ beta,
                                                  float* __restrict__ out) {
    int bx = blockIdx.x;            // 0..4095
    int gb = bx >> 4;               // 0..255
    int chunk = bx & 15;
    int b = gb >> 3, g = gb & 7;
    size_t base = ((size_t)(b*NFEAT + g*GS))*HW + chunk*256 + threadIdx.x;
    const float* wg = wmT + (size_t)g*1024;
    const float* bg = beta + (size_t)g*GS;

    float v[32];
    #pragma unroll
    for (int d = 0; d < 32; ++d) v[d] = x[base + (size_t)d*HW];

    float acc[32];
    #pragma unroll
    for (int c = 0; c < 32; ++c) acc[c] = bg[c];

    #pragma unroll
    for (int d = 0; d < 32; ++d) {
        float vd = v[d];
        #pragma unroll
        for (int c = 0; c < 32; ++c) acc[c] = fmaf(wg[d*32 + c], vd, acc[c]);
    }

    #pragma unroll
    for (int c = 0; c < 32; ++c) out[base + (size_t)c*HW] = acc[c];
}

extern "C" void kernel_launch(void* const* d_in, const int* in_sizes, int n_in,
                              void* d_out, int out_size, void* d_ws, size_t ws_size,
                              hipStream_t stream) {
    const float* x      = (const float*)d_in[0];
    const float* weight = (const float*)d_in[1];
    const float* bias   = (const float*)d_in[2];
    float* out = (float*)d_out;
    float* ws  = (float*)d_ws;

    float* Rpart = ws;
    float* Spart = ws + SPART_OFF;
    float* wmT   = ws + WMT_OFF;
    float* beta  = ws + BETA_OFF;

    dbn_stats <<<512, 1024, 0, stream>>>(x, Rpart, Spart);
    dbn_solver<<<NG, 1024, 0, stream>>>(Rpart, Spart, weight, bias, wmT, beta);
    dbn_whiten<<<4096, 256, 0, stream>>>(x, wmT, beta, out);
}